// Round 14
// baseline (98.635 us; speedup 1.0000x reference)
//
#include <hip/hip_runtime.h>

#define NN 4096
#define CC 256
#define DQ 32

typedef __attribute__((ext_vector_type(8))) short short8;
typedef __attribute__((ext_vector_type(4))) float f32x4;

__device__ __forceinline__ unsigned short f32_to_bf16(float f) {
  unsigned int u = __float_as_uint(f);
  u += 0x7fffu + ((u >> 16) & 1u);   // RNE
  return (unsigned short)(u >> 16);
}

__device__ __forceinline__ float bf16_to_f32(unsigned short u) {
  return __uint_as_float(((unsigned int)u) << 16);
}

__device__ __forceinline__ float exp2_hw(float f) {
  return __builtin_amdgcn_exp2f(f);   // v_exp_f32: D = 2^S0
}

__device__ __forceinline__ unsigned cvt_pk_bf16(float lo, float hi) {
  unsigned r;
  asm("v_cvt_pk_bf16_f32 %0, %1, %2" : "=v"(r) : "v"(lo), "v"(hi));
  return r;
}

__device__ __forceinline__ void gld16(const void* g, void* l) {
  __builtin_amdgcn_global_load_lds(
      (__attribute__((address_space(1))) void*)(g),
      (__attribute__((address_space(3))) void*)(l), 16, 0, 0);
}

// ---------------- kernel 1: weights/bias convert ----------------
__global__ __launch_bounds__(256) void wconv_kernel(
    const float* qw, const float* kw, const float* vw,
    const float* qb, const float* kb, const float* vb,
    unsigned short* Wcat, float* bcat) {
  int id = blockIdx.x * 256 + threadIdx.x;
  if (id < 320 * 256) {
    int row = id >> 8;
    float v;
    if (row < 32) v = qw[id];
    else if (row < 64) v = kw[id - 32 * 256];
    else v = vw[id - 64 * 256];
    Wcat[id] = f32_to_bf16(v);
  }
  if (id < 320) {
    float v;
    if (id < 32) v = qb[id];
    else if (id < 64) v = kb[id - 32];
    else v = vb[id - 64];
    bcat[id] = v;
  }
}

// ---------------- kernel 2: QKV projection, 512 blocks x 32 n --------------
__global__ __launch_bounds__(256, 2) void proj_kernel(
    const float* x, const unsigned short* Wcat, const float* bcat,
    unsigned short* Qt, unsigned short* Kt, unsigned short* V) {
  int bid = blockIdx.x;
  int b = bid >> 7, nb = bid & 127;        // 32-n blocks
  int tid = threadIdx.x, lane = tid & 63, w = tid >> 6;
  int l15 = lane & 15, h = lane >> 4;

  __shared__ unsigned short xT[32][272];   // padded rows
  __shared__ unsigned short vbuf[CC][32];
  {
    const float* xb = x + (size_t)b * CC * NN + nb * 32;
    int c0 = tid >> 3, n4 = (tid & 7) * 4;
#pragma unroll
    for (int i = 0; i < 8; i++) {
      int c = c0 + i * 32;
      f32x4 v = *(const f32x4*)(xb + (size_t)c * NN + n4);
#pragma unroll
      for (int j = 0; j < 4; j++) xT[n4 + j][c] = f32_to_bf16(v[j]);
    }
  }
  __syncthreads();

  short8 af0[8], af1[8];
#pragma unroll
  for (int ks = 0; ks < 8; ks++) {
    af0[ks] = *(const short8*)(&xT[l15][ks * 32 + h * 8]);
    af1[ks] = *(const short8*)(&xT[16 + l15][ks * 32 + h * 8]);
  }

  f32x4 acc0[5], acc1[5];
#pragma unroll
  for (int t = 0; t < 5; t++)
#pragma unroll
    for (int r = 0; r < 4; r++) { acc0[t][r] = 0.f; acc1[t][r] = 0.f; }

#pragma unroll
  for (int ks = 0; ks < 8; ks++) {
#pragma unroll
    for (int d = 0; d < 5; d++) {
      int dt = w * 5 + d;
      short8 bfr = *(const short8*)(Wcat + (size_t)(dt * 16 + l15) * CC + ks * 32 + h * 8);
      acc0[d] = __builtin_amdgcn_mfma_f32_16x16x32_bf16(af0[ks], bfr, acc0[d], 0, 0, 0);
      acc1[d] = __builtin_amdgcn_mfma_f32_16x16x32_bf16(af1[ks], bfr, acc1[d], 0, 0, 0);
    }
  }

  unsigned short* Qtb = Qt + (size_t)b * NN * DQ;
  unsigned short* Ktb = Kt + (size_t)b * NN * DQ;
#pragma unroll
  for (int d = 0; d < 5; d++) {
    int dt = w * 5 + d;
    float bias = bcat[dt * 16 + l15];
    if (dt < 4) {
      float scale = dt < 2 ? 1.44269504f : 1.0f;   // Q prescaled by log2e
      unsigned short* dst = dt < 2 ? Qtb : Ktb;
      int dd = (dt & 1) * 16 + l15;
#pragma unroll
      for (int r = 0; r < 4; r++) {
        int nA = nb * 32 + h * 4 + r;
        dst[(size_t)nA * DQ + dd] = f32_to_bf16((acc0[d][r] + bias) * scale);
        dst[(size_t)(nA + 16) * DQ + dd] = f32_to_bf16((acc1[d][r] + bias) * scale);
      }
    } else {
      int c = (dt - 4) * 16 + l15;
#pragma unroll
      for (int r = 0; r < 4; r++) {
        vbuf[c][h * 4 + r] = f32_to_bf16(acc0[d][r] + bias);
        vbuf[c][16 + h * 4 + r] = f32_to_bf16(acc1[d][r] + bias);
      }
    }
  }
  __syncthreads();
  unsigned short* Vb = V + (size_t)b * CC * NN + nb * 32;
  int c = tid;
#pragma unroll
  for (int k = 0; k < 4; k++)
    *(f32x4*)(Vb + (size_t)c * NN + k * 8) = *(const f32x4*)(&vbuf[c][k * 8]);
}

// ---------------- kernel 3: flash attention, software-pipelined ----------
// 256 blocks x 1024 thr (16 waves = 4/SIMD). Block = (b, mh m-half, nb 128-n).
// Per step (64-m chunk), ONE barrier. R12-measured-best order:
//   kload(T,LDS) | stage V(T+1),K(T+2) | QK(T) | softmax | P-write | PV(T-1) | bar
// K staged in LDS (kills 8x redundant L2 K-loads); counted vmcnt before the
// barrier keeps the 3 newest loads (V(T+1)x2 + K(T+2)) in flight, drains the
// rest (incl. K(T+1), consumed next step). pbuf: 64B rows, 16B-slot XOR
// swizzle (bank floor). vbuf/kbuf: 3-slot rings.
__global__ __launch_bounds__(1024, 4) void attn_kernel(
    const unsigned short* Qt, const unsigned short* Kt, const unsigned short* V,
    unsigned short* Apart, float* rspart) {
  int bid = blockIdx.x;
  int b  = (bid & 7) >> 1;               // XCD pair {2b,2b+1}
  int mh = bid & 1;
  int nb = bid >> 3;                     // [0,32)
  int tid = threadIdx.x, lane = tid & 63, w = tid >> 6;   // w in [0,16)
  int grp = w >> 3, wq = w & 7, wc = w & 3, ntb = (w >> 2) & 1;
  int l15 = lane & 15, h = lane >> 4;
  int n0 = nb * 128 + wq * 16;
  int m0base = mh * 2048;

  const unsigned short* Qtb = Qt + (size_t)b * NN * DQ;
  const unsigned short* Ktb = Kt + (size_t)b * NN * DQ;
  const unsigned short* Vb  = V  + (size_t)b * CC * NN;

  // LDS: vbuf 3x32768 @0; kbuf 3x4096 @98304; pbuf 2x16384 @110592. =143360 B
  __shared__ __align__(16) char ldsb[143360];

  short8 qf = *(const short8*)(Qtb + (size_t)(n0 + l15) * DQ + h * 8);

  f32x4 acc[16];   // [ct*4+i]: c = wc*64+ct*16+h*4+r ; n = (ntb*4+i)*16+l15
#pragma unroll
  for (int t = 0; t < 16; t++)
#pragma unroll
    for (int r = 0; r < 4; r++) acc[t][r] = 0.f;
  float rs = 0.f;

  f32x4 zero4;
#pragma unroll
  for (int r = 0; r < 4; r++) zero4[r] = 0.f;

  // Stage V chunk T (256c x 64m = 32 KB): 2 gld16/thread.
  auto stage_v = [&](char* vdst, int T) {
    int m0 = m0base + T * 64;
#pragma unroll
    for (int it = 0; it < 2; it++) {
      int idx = it * 1024 + tid;
      int c = idx >> 3, sub = idx & 7;
      int moff = (sub ^ (c & 7)) * 8;    // source pre-swizzle
      gld16(Vb + (size_t)c * NN + m0 + moff, vdst + idx * 16);
    }
  };
  // Stage K chunk T (64m x 32d = 4 KB): lanes 0-15 of each wave, 1 gld16/wave.
  // Row = 64 B (4 slots); physical slot p holds logical d-slot p ^ (row&3).
  auto stage_k = [&](char* kdst, int T) {
    int m0 = m0base + T * 64;
    int r = w * 4 + (lane >> 2);
    int lsl = (lane & 3) ^ ((lane >> 2) & 3);
    if (lane < 16)
      gld16(Ktb + (size_t)(m0 + r) * DQ + lsl * 8, kdst + w * 256 + lane * 16);
  };

  short8 kA[2];
  auto kload_lds = [&](const char* kb) {
#pragma unroll
    for (int s = 0; s < 2; s++) {
      int row = grp * 32 + s * 16 + l15;
      kA[s] = *(const short8*)(kb + row * 64 + ((h ^ (l15 & 3)) * 16));
    }
  };

  // PV for one chunk: A = V rows (c), B = P tiles of own grp (k = 32 m).
  auto pvstep = [&](const char* vb2, const char* prd) {
    const char* pb = prd + (grp * 8 + ntb * 4) * 1024 + l15 * 64 + ((h ^ (l15 & 3)) * 16);
    short8 pf0 = *(const short8*)(pb + 0 * 1024);
    short8 pf1 = *(const short8*)(pb + 1 * 1024);
    short8 pf2 = *(const short8*)(pb + 2 * 1024);
    short8 pf3 = *(const short8*)(pb + 3 * 1024);
#pragma unroll
    for (int ct = 0; ct < 4; ct++) {
      int c = wc * 64 + ct * 16 + l15;
      int sub = (grp * 4 + h) ^ (c & 7);
      short8 vf = *(const short8*)(vb2 + c * 128 + sub * 16);
      acc[ct * 4 + 0] = __builtin_amdgcn_mfma_f32_16x16x32_bf16(vf, pf0, acc[ct * 4 + 0], 0, 0, 0);
      acc[ct * 4 + 1] = __builtin_amdgcn_mfma_f32_16x16x32_bf16(vf, pf1, acc[ct * 4 + 1], 0, 0, 0);
      acc[ct * 4 + 2] = __builtin_amdgcn_mfma_f32_16x16x32_bf16(vf, pf2, acc[ct * 4 + 2], 0, 0, 0);
      acc[ct * 4 + 3] = __builtin_amdgcn_mfma_f32_16x16x32_bf16(vf, pf3, acc[ct * 4 + 3], 0, 0, 0);
    }
  };

  char* vpv  = ldsb + 2 * 32768;   // V(T-1) (PV reads)
  char* vrdy = ldsb + 0 * 32768;   // V(T)
  char* vstg = ldsb + 1 * 32768;   // V(T+1) (staging)
  char* kcur  = ldsb + 98304 + 0 * 4096;   // K(T)   (read this step)
  char* knext = ldsb + 98304 + 1 * 4096;   // K(T+1) (in flight)
  char* kstg2 = ldsb + 98304 + 2 * 4096;   // K(T+2) (staging)
  char* pbw  = ldsb + 110592;              // P bank written this step
  char* pbr  = ldsb + 110592 + 16384;      // P bank read (P(T-1))

  stage_v(vrdy, 0);
  stage_k(kcur, 0);
  stage_k(knext, 1);
  asm volatile("s_waitcnt vmcnt(0)" ::: "memory");
  __syncthreads();

  for (int T = 0; T < 32; T++) {
    kload_lds(kcur);                       // K(T) from LDS (drained)
    if (T + 1 < 32) stage_v(vstg, T + 1);
    if (T + 2 < 32) stage_k(kstg2, T + 2);
    // QK(T): scores for (n = l15, m' = grp*32 + s*16 + h*4 + r)
    f32x4 st0 = __builtin_amdgcn_mfma_f32_16x16x32_bf16(kA[0], qf, zero4, 0, 0, 0);
    f32x4 st1 = __builtin_amdgcn_mfma_f32_16x16x32_bf16(kA[1], qf, zero4, 0, 0, 0);
    // no-max softmax (exp2 domain; Q prescaled by log2e)
    float e0 = exp2_hw(st0[0]), e1 = exp2_hw(st0[1]);
    float e2 = exp2_hw(st0[2]), e3 = exp2_hw(st0[3]);
    float f0 = exp2_hw(st1[0]), f1 = exp2_hw(st1[1]);
    float f2 = exp2_hw(st1[2]), f3 = exp2_hw(st1[3]);
    rs += ((e0 + e1) + (e2 + e3)) + ((f0 + f1) + (f2 + f3));
    int2 q0, q1;
    q0.x = (int)cvt_pk_bf16(e0, e1); q0.y = (int)cvt_pk_bf16(e2, e3);
    q1.x = (int)cvt_pk_bf16(f0, f1); q1.y = (int)cvt_pk_bf16(f2, f3);
    {   // P-write(T): 64B rows, slot-XOR swizzle
      char* pw = pbw + w * 1024 + l15 * 64;
      int s0 = ((h >> 1) ^ (l15 & 3));
      int s1 = ((2 + (h >> 1)) ^ (l15 & 3));
      *(int2*)(pw + s0 * 16 + (h & 1) * 8) = q0;
      *(int2*)(pw + s1 * 16 + (h & 1) * 8) = q1;
    }
    if (T > 0) pvstep(vpv, pbr);           // PV(T-1): measured-best position
    // Drain all but the 3 newest loads (V(T+1)x2, K(T+2)); K(T+1) completes.
    if (T < 30)      asm volatile("s_waitcnt vmcnt(3)" ::: "memory");
    else if (T == 30) asm volatile("s_waitcnt vmcnt(2)" ::: "memory");
    else              asm volatile("s_waitcnt vmcnt(0)" ::: "memory");
    asm volatile("s_waitcnt lgkmcnt(0)" ::: "memory");
    __builtin_amdgcn_s_barrier();
    asm volatile("" ::: "memory");
    // rotate rings + swap P banks
    char* t0 = vpv; vpv = vrdy; vrdy = vstg; vstg = t0;
    char* t1 = kcur; kcur = knext; knext = kstg2; kstg2 = t1;
    char* t2 = pbw; pbw = pbr; pbr = t2;
  }
  pvstep(vpv, pbr);   // PV(31)

  // rs: reduce h-partials; write per-(mh,grp) quarter to global.
  rs += __shfl_xor(rs, 16);
  rs += __shfl_xor(rs, 32);
  if (h == 0)
    rspart[(size_t)(b * 4 + mh * 2 + grp) * NN + nb * 128 + wq * 16 + l15] = rs;

  // grp-merge acc (w with w^8) via pbuf region -- ALL STATIC indexing.
  __syncthreads();
  char* pregion = ldsb + 110592;   // 32 KB
#pragma unroll
  for (int r = 0; r < 4; r++) {
    if (grp == 1) {
#pragma unroll
      for (int i = 0; i < 4; i++)
        *(f32x4*)(pregion + (w - 8) * 4096 + i * 1024 + lane * 16) = acc[r * 4 + i];
    }
    __syncthreads();
    if (grp == 0) {
#pragma unroll
      for (int i = 0; i < 4; i++) {
        f32x4 p = *(const f32x4*)(pregion + w * 4096 + i * 1024 + lane * 16);
#pragma unroll
        for (int q = 0; q < 4; q++) acc[r * 4 + i][q] += p[q];
      }
    }
    __syncthreads();
  }

  unsigned short* ldsus = (unsigned short*)ldsb;
  if (grp == 0) {   // merged A (bf16) into vbuf area as [c][128 n]
#pragma unroll
    for (int ct = 0; ct < 4; ct++)
#pragma unroll
      for (int i = 0; i < 4; i++)
#pragma unroll
        for (int r = 0; r < 4; r++) {
          int c = wc * 64 + ct * 16 + h * 4 + r;
          int n = (ntb * 4 + i) * 16 + l15;
          ldsus[c * 128 + n] = f32_to_bf16(acc[ct * 4 + i][r]);
        }
  }
  __syncthreads();
  {
    unsigned short* Adst = Apart + (size_t)(b * 2 + mh) * CC * NN + nb * 128;
    int c = tid >> 2, seg = tid & 3;
    const f32x4* src = (const f32x4*)(ldsb + c * 256 + seg * 64);
#pragma unroll
    for (int k = 0; k < 4; k++)
      *(f32x4*)(Adst + (size_t)c * NN + seg * 32 + k * 8) = src[k];
  }
}

// ---------------- kernel 4: fuse m-halves + gamma*O + x ----------------
__global__ __launch_bounds__(256) void fuse_kernel(
    const unsigned short* Apart, const float* rspart, const float* x,
    const float* gamma, float* out) {
  int bid = blockIdx.x;                  // 2048 = 4 b x 256 c x 2 half
  int b = bid >> 9, c = (bid >> 1) & 255, half = bid & 1;
  int n0 = half * 2048 + threadIdx.x * 8;

  short8 a0 = *(const short8*)(Apart + ((size_t)(b * 2 + 0) * CC + c) * NN + n0);
  short8 a1 = *(const short8*)(Apart + ((size_t)(b * 2 + 1) * CC + c) * NN + n0);

  const float* rp = rspart + (size_t)b * 4 * NN + n0;
  f32x4 rlo, rhi;
#pragma unroll
  for (int q = 0; q < 4; q++) { rlo[q] = 0.f; rhi[q] = 0.f; }
#pragma unroll
  for (int p = 0; p < 4; p++) {
    f32x4 ra = *(const f32x4*)(rp + (size_t)p * NN);
    f32x4 rb = *(const f32x4*)(rp + (size_t)p * NN + 4);
#pragma unroll
    for (int q = 0; q < 4; q++) { rlo[q] += ra[q]; rhi[q] += rb[q]; }
  }

  const float* xp = x + ((size_t)b * CC + c) * NN + n0;
  f32x4 x0 = *(const f32x4*)(xp), x1 = *(const f32x4*)(xp + 4);
  float g = gamma[0];

  f32x4 o0, o1;
#pragma unroll
  for (int q = 0; q < 4; q++) {
    float a = bf16_to_f32((unsigned short)a0[q]) + bf16_to_f32((unsigned short)a1[q]);
    o0[q] = g * a / rlo[q] + x0[q];
    float a2 = bf16_to_f32((unsigned short)a0[q + 4]) + bf16_to_f32((unsigned short)a1[q + 4]);
    o1[q] = g * a2 / rhi[q] + x1[q];
  }
  float* op = out + ((size_t)b * CC + c) * NN + n0;
  *(f32x4*)op = o0;
  *(f32x4*)(op + 4) = o1;
}

extern "C" void kernel_launch(void* const* d_in, const int* in_sizes, int n_in,
                              void* d_out, int out_size, void* d_ws, size_t ws_size,
                              hipStream_t stream) {
  (void)in_sizes; (void)n_in; (void)out_size; (void)ws_size;
  const float* x  = (const float*)d_in[0];
  const float* qw = (const float*)d_in[1];
  const float* qb = (const float*)d_in[2];
  const float* kw = (const float*)d_in[3];
  const float* kb = (const float*)d_in[4];
  const float* vw = (const float*)d_in[5];
  const float* vb = (const float*)d_in[6];
  const float* gamma = (const float*)d_in[7];
  float* out = (float*)d_out;

  char* ws = (char*)d_ws;
  unsigned short* Wcat  = (unsigned short*)(ws);                       // 160 KB
  float*          bcat  = (float*)(ws + 163840);                       // 1.25 KB
  unsigned short* Qt    = (unsigned short*)(ws + 165120);              // 1 MB
  unsigned short* Kt    = (unsigned short*)(ws + 1213696);             // 1 MB
  unsigned short* V     = (unsigned short*)(ws + 2262272);             // 8 MB
  unsigned short* Apart = (unsigned short*)(ws + 10650880);            // 16 MB
  float*          rsprt = (float*)(ws + 27428096);                     // 256 KB

  hipLaunchKernelGGL(wconv_kernel, dim3(320), dim3(256), 0, stream,
                     qw, kw, vw, qb, kb, vb, Wcat, bcat);
  hipLaunchKernelGGL(proj_kernel, dim3(512), dim3(256), 0, stream,
                     x, Wcat, bcat, Qt, Kt, V);
  hipLaunchKernelGGL(attn_kernel, dim3(256), dim3(1024), 0, stream,
                     Qt, Kt, V, Apart, rsprt);
  hipLaunchKernelGGL(fuse_kernel, dim3(2048), dim3(256), 0, stream,
                     Apart, rsprt, x, gamma, out);
}

// Round 15
// 90.195 us; speedup vs baseline: 1.0936x; 1.0936x over previous
//
#include <hip/hip_runtime.h>

#define NN 4096
#define CC 256
#define DQ 32

typedef __attribute__((ext_vector_type(8))) short short8;
typedef __attribute__((ext_vector_type(4))) float f32x4;

__device__ __forceinline__ unsigned short f32_to_bf16(float f) {
  unsigned int u = __float_as_uint(f);
  u += 0x7fffu + ((u >> 16) & 1u);   // RNE
  return (unsigned short)(u >> 16);
}

__device__ __forceinline__ float bf16_to_f32(unsigned short u) {
  return __uint_as_float(((unsigned int)u) << 16);
}

__device__ __forceinline__ float exp2_hw(float f) {
  return __builtin_amdgcn_exp2f(f);   // v_exp_f32: D = 2^S0
}

__device__ __forceinline__ unsigned cvt_pk_bf16(float lo, float hi) {
  unsigned r;
  asm("v_cvt_pk_bf16_f32 %0, %1, %2" : "=v"(r) : "v"(lo), "v"(hi));
  return r;
}

__device__ __forceinline__ void gld16(const void* g, void* l) {
  __builtin_amdgcn_global_load_lds(
      (__attribute__((address_space(1))) void*)(g),
      (__attribute__((address_space(3))) void*)(l), 16, 0, 0);
}

// ---------------- kernel 1: weights/bias convert ----------------
__global__ __launch_bounds__(256) void wconv_kernel(
    const float* qw, const float* kw, const float* vw,
    const float* qb, const float* kb, const float* vb,
    unsigned short* Wcat, float* bcat) {
  int id = blockIdx.x * 256 + threadIdx.x;
  if (id < 320 * 256) {
    int row = id >> 8;
    float v;
    if (row < 32) v = qw[id];
    else if (row < 64) v = kw[id - 32 * 256];
    else v = vw[id - 64 * 256];
    Wcat[id] = f32_to_bf16(v);
  }
  if (id < 320) {
    float v;
    if (id < 32) v = qb[id];
    else if (id < 64) v = kb[id - 32];
    else v = vb[id - 64];
    bcat[id] = v;
  }
}

// ---------------- kernel 2: QKV projection, 512 blocks x 32 n --------------
// Wave w: dt-range w*5..w*5+4 x BOTH 16-n tiles (each Wcat load feeds 2 MFMAs).
__global__ __launch_bounds__(256, 2) void proj_kernel(
    const float* x, const unsigned short* Wcat, const float* bcat,
    unsigned short* Qt, unsigned short* Kt, unsigned short* V) {
  int bid = blockIdx.x;
  int b = bid >> 7, nb = bid & 127;        // 32-n blocks
  int tid = threadIdx.x, lane = tid & 63, w = tid >> 6;
  int l15 = lane & 15, h = lane >> 4;

  __shared__ unsigned short xT[32][272];   // padded rows
  __shared__ unsigned short vbuf[CC][32];
  {
    const float* xb = x + (size_t)b * CC * NN + nb * 32;
    int c0 = tid >> 3, n4 = (tid & 7) * 4;
#pragma unroll
    for (int i = 0; i < 8; i++) {
      int c = c0 + i * 32;
      f32x4 v = *(const f32x4*)(xb + (size_t)c * NN + n4);
#pragma unroll
      for (int j = 0; j < 4; j++) xT[n4 + j][c] = f32_to_bf16(v[j]);
    }
  }
  __syncthreads();

  short8 af0[8], af1[8];
#pragma unroll
  for (int ks = 0; ks < 8; ks++) {
    af0[ks] = *(const short8*)(&xT[l15][ks * 32 + h * 8]);
    af1[ks] = *(const short8*)(&xT[16 + l15][ks * 32 + h * 8]);
  }

  f32x4 acc0[5], acc1[5];
#pragma unroll
  for (int t = 0; t < 5; t++)
#pragma unroll
    for (int r = 0; r < 4; r++) { acc0[t][r] = 0.f; acc1[t][r] = 0.f; }

#pragma unroll
  for (int ks = 0; ks < 8; ks++) {
#pragma unroll
    for (int d = 0; d < 5; d++) {
      int dt = w * 5 + d;
      short8 bfr = *(const short8*)(Wcat + (size_t)(dt * 16 + l15) * CC + ks * 32 + h * 8);
      acc0[d] = __builtin_amdgcn_mfma_f32_16x16x32_bf16(af0[ks], bfr, acc0[d], 0, 0, 0);
      acc1[d] = __builtin_amdgcn_mfma_f32_16x16x32_bf16(af1[ks], bfr, acc1[d], 0, 0, 0);
    }
  }

  unsigned short* Qtb = Qt + (size_t)b * NN * DQ;
  unsigned short* Ktb = Kt + (size_t)b * NN * DQ;
#pragma unroll
  for (int d = 0; d < 5; d++) {
    int dt = w * 5 + d;
    float bias = bcat[dt * 16 + l15];
    if (dt < 4) {
      float scale = dt < 2 ? 1.44269504f : 1.0f;   // Q prescaled by log2e
      unsigned short* dst = dt < 2 ? Qtb : Ktb;
      int dd = (dt & 1) * 16 + l15;
#pragma unroll
      for (int r = 0; r < 4; r++) {
        int nA = nb * 32 + h * 4 + r;
        dst[(size_t)nA * DQ + dd] = f32_to_bf16((acc0[d][r] + bias) * scale);
        dst[(size_t)(nA + 16) * DQ + dd] = f32_to_bf16((acc1[d][r] + bias) * scale);
      }
    } else {
      int c = (dt - 4) * 16 + l15;
#pragma unroll
      for (int r = 0; r < 4; r++) {
        vbuf[c][h * 4 + r] = f32_to_bf16(acc0[d][r] + bias);
        vbuf[c][16 + h * 4 + r] = f32_to_bf16(acc1[d][r] + bias);
      }
    }
  }
  __syncthreads();
  unsigned short* Vb = V + (size_t)b * CC * NN + nb * 32;
  int c = tid;
#pragma unroll
  for (int k = 0; k < 4; k++)
    *(f32x4*)(Vb + (size_t)c * NN + k * 8) = *(const f32x4*)(&vbuf[c][k * 8]);
}

// ---------------- kernel 3: flash attention (R12 measured-best config) ----
// 256 blocks x 1024 thr (16 waves = 4/SIMD). Block = (b, mh m-half, nb 128-n).
// Per step, ONE barrier:
//   stage(T+1) | QK(T) | kload(T+1,global) | softmax | P-write | PV(T-1) | bar
// pbuf 80-B rows (2-way bank aliasing = free; 64B-XOR variant was 4-way, -9us).
// Implicit counted vmcnt: compiler's kA-wait at QK(T) FIFO-drains stage(T)
// while stage(T+1) stays in flight. setprio around PV (R12-measured).
__global__ __launch_bounds__(1024, 4) void attn_kernel(
    const unsigned short* Qt, const unsigned short* Kt, const unsigned short* V,
    unsigned short* Apart, float* rspart) {
  int bid = blockIdx.x;
  int b  = (bid & 7) >> 1;               // XCD pair {2b,2b+1}
  int mh = bid & 1;
  int nb = bid >> 3;                     // [0,32)
  int tid = threadIdx.x, lane = tid & 63, w = tid >> 6;   // w in [0,16)
  int grp = w >> 3, wq = w & 7, wc = w & 3, ntb = (w >> 2) & 1;
  int l15 = lane & 15, h = lane >> 4;
  int n0 = nb * 128 + wq * 16;
  int m0base = mh * 2048;

  const unsigned short* Qtb = Qt + (size_t)b * NN * DQ;
  const unsigned short* Ktb = Kt + (size_t)b * NN * DQ;
  const unsigned short* Vb  = V  + (size_t)b * CC * NN;

  // LDS: vbuf 3 x 32768 at 0; pbuf 2 x 20480 at 98304. Total 139264 B.
  __shared__ __align__(16) char ldsb[139264];

  short8 qf = *(const short8*)(Qtb + (size_t)(n0 + l15) * DQ + h * 8);

  f32x4 acc[16];   // [ct*4+i]: c = wc*64+ct*16+h*4+r ; n = (ntb*4+i)*16+l15
#pragma unroll
  for (int t = 0; t < 16; t++)
#pragma unroll
    for (int r = 0; r < 4; r++) acc[t][r] = 0.f;
  float rs = 0.f;

  f32x4 zero4;
#pragma unroll
  for (int r = 0; r < 4; r++) zero4[r] = 0.f;

  // Stage chunk T (256c x 64m = 32 KB) into ring slot: 2 gld16/thread.
  auto stage_to = [&](char* dst, int T) {
    int m0 = m0base + T * 64;
#pragma unroll
    for (int it = 0; it < 2; it++) {
      int idx = it * 1024 + tid;
      int c = idx >> 3, sub = idx & 7;
      int moff = (sub ^ (c & 7)) * 8;    // source pre-swizzle
      gld16(Vb + (size_t)c * NN + m0 + moff, dst + idx * 16);
    }
  };

  short8 kA[2];
  auto kload = [&](int T) {
    int m0 = m0base + T * 64 + grp * 32;
#pragma unroll
    for (int s = 0; s < 2; s++)
      kA[s] = *(const short8*)(Ktb + (size_t)(m0 + s * 16 + l15) * DQ + h * 8);
  };

  // PV for one chunk: A = V rows (c), B = P tiles of own grp (k = 32 m).
  auto pvstep = [&](const char* vb2, const char* prd) {
    const char* pb = prd + (grp * 8 + ntb * 4) * 1280 + l15 * 80 + h * 16;
    __builtin_amdgcn_s_setprio(1);
    short8 pf0 = *(const short8*)(pb + 0 * 1280);
    short8 pf1 = *(const short8*)(pb + 1 * 1280);
    short8 pf2 = *(const short8*)(pb + 2 * 1280);
    short8 pf3 = *(const short8*)(pb + 3 * 1280);
#pragma unroll
    for (int ct = 0; ct < 4; ct++) {
      int c = wc * 64 + ct * 16 + l15;
      int sub = (grp * 4 + h) ^ (c & 7);
      short8 vf = *(const short8*)(vb2 + c * 128 + sub * 16);
      acc[ct * 4 + 0] = __builtin_amdgcn_mfma_f32_16x16x32_bf16(vf, pf0, acc[ct * 4 + 0], 0, 0, 0);
      acc[ct * 4 + 1] = __builtin_amdgcn_mfma_f32_16x16x32_bf16(vf, pf1, acc[ct * 4 + 1], 0, 0, 0);
      acc[ct * 4 + 2] = __builtin_amdgcn_mfma_f32_16x16x32_bf16(vf, pf2, acc[ct * 4 + 2], 0, 0, 0);
      acc[ct * 4 + 3] = __builtin_amdgcn_mfma_f32_16x16x32_bf16(vf, pf3, acc[ct * 4 + 3], 0, 0, 0);
    }
    __builtin_amdgcn_s_setprio(0);
  };

  char* vpv  = ldsb + 2 * 32768;   // chunk T-1 (PV reads)
  char* vrdy = ldsb + 0 * 32768;   // chunk T   (staged, ready)
  char* vstg = ldsb + 1 * 32768;   // chunk T+1 (staging)
  char* pbw  = ldsb + 98304;           // P bank written this step
  char* pbr  = ldsb + 98304 + 20480;   // P bank read (P(T-1))

  stage_to(vrdy, 0);
  kload(0);

  for (int T = 0; T < 32; T++) {
    if (T + 1 < 32) stage_to(vstg, T + 1);
    // QK(T): scores for (n = l15, m' = grp*32 + s*16 + h*4 + r)
    f32x4 st0 = __builtin_amdgcn_mfma_f32_16x16x32_bf16(kA[0], qf, zero4, 0, 0, 0);
    f32x4 st1 = __builtin_amdgcn_mfma_f32_16x16x32_bf16(kA[1], qf, zero4, 0, 0, 0);
    if (T + 1 < 32) kload(T + 1);   // WAR after QK use; compiler orders
    // no-max softmax (exp2 domain; Q prescaled by log2e)
    float e0 = exp2_hw(st0[0]), e1 = exp2_hw(st0[1]);
    float e2 = exp2_hw(st0[2]), e3 = exp2_hw(st0[3]);
    float f0 = exp2_hw(st1[0]), f1 = exp2_hw(st1[1]);
    float f2 = exp2_hw(st1[2]), f3 = exp2_hw(st1[3]);
    rs += ((e0 + e1) + (e2 + e3)) + ((f0 + f1) + (f2 + f3));
    int2 q0, q1;
    q0.x = (int)cvt_pk_bf16(e0, e1); q0.y = (int)cvt_pk_bf16(e2, e3);
    q1.x = (int)cvt_pk_bf16(f0, f1); q1.y = (int)cvt_pk_bf16(f2, f3);
    {   // P-write(T) -> pbw (issues early; retires during PV)
      char* pw = pbw + w * 1280 + l15 * 80 + h * 8;
      *(int2*)(pw + 0)  = q0;   // s=0: bytes h*8 .. +7
      *(int2*)(pw + 32) = q1;   // s=1: bytes 32+h*8 .. +7
    }
    if (T > 0) pvstep(vpv, pbr);   // PV(T-1) last-before-barrier (measured best)
    asm volatile("s_waitcnt lgkmcnt(0)" ::: "memory");
    __builtin_amdgcn_s_barrier();
    asm volatile("" ::: "memory");
    // rotate ring + swap P banks
    char* t0 = vpv; vpv = vrdy; vrdy = vstg; vstg = t0;
    char* t1 = pbw; pbw = pbr; pbr = t1;
  }
  pvstep(vpv, pbr);   // PV(31)

  // rs: reduce h-partials; write per-(mh,grp) quarter to global.
  rs += __shfl_xor(rs, 16);
  rs += __shfl_xor(rs, 32);
  if (h == 0)
    rspart[(size_t)(b * 4 + mh * 2 + grp) * NN + nb * 128 + wq * 16 + l15] = rs;

  // grp-merge acc (w with w^8) via pbuf region -- ALL STATIC indexing.
  __syncthreads();
  char* pregion = ldsb + 98304;   // 40 KB >= 32 KB per round
#pragma unroll
  for (int r = 0; r < 4; r++) {
    if (grp == 1) {
#pragma unroll
      for (int i = 0; i < 4; i++)
        *(f32x4*)(pregion + (w - 8) * 4096 + i * 1024 + lane * 16) = acc[r * 4 + i];
    }
    __syncthreads();
    if (grp == 0) {
#pragma unroll
      for (int i = 0; i < 4; i++) {
        f32x4 p = *(const f32x4*)(pregion + w * 4096 + i * 1024 + lane * 16);
#pragma unroll
        for (int q = 0; q < 4; q++) acc[r * 4 + i][q] += p[q];
      }
    }
    __syncthreads();
  }

  unsigned short* ldsus = (unsigned short*)ldsb;
  if (grp == 0) {   // merged A (bf16) into vbuf area as [c][128 n]
#pragma unroll
    for (int ct = 0; ct < 4; ct++)
#pragma unroll
      for (int i = 0; i < 4; i++)
#pragma unroll
        for (int r = 0; r < 4; r++) {
          int c = wc * 64 + ct * 16 + h * 4 + r;
          int n = (ntb * 4 + i) * 16 + l15;
          ldsus[c * 128 + n] = f32_to_bf16(acc[ct * 4 + i][r]);
        }
  }
  __syncthreads();
  {
    unsigned short* Adst = Apart + (size_t)(b * 2 + mh) * CC * NN + nb * 128;
    int c = tid >> 2, seg = tid & 3;
    const f32x4* src = (const f32x4*)(ldsb + c * 256 + seg * 64);
#pragma unroll
    for (int k = 0; k < 4; k++)
      *(f32x4*)(Adst + (size_t)c * NN + seg * 32 + k * 8) = src[k];
  }
}

// ---------------- kernel 4: fuse m-halves + gamma*O + x ----------------
__global__ __launch_bounds__(256) void fuse_kernel(
    const unsigned short* Apart, const float* rspart, const float* x,
    const float* gamma, float* out) {
  int bid = blockIdx.x;                  // 2048 = 4 b x 256 c x 2 half
  int b = bid >> 9, c = (bid >> 1) & 255, half = bid & 1;
  int n0 = half * 2048 + threadIdx.x * 8;

  short8 a0 = *(const short8*)(Apart + ((size_t)(b * 2 + 0) * CC + c) * NN + n0);
  short8 a1 = *(const short8*)(Apart + ((size_t)(b * 2 + 1) * CC + c) * NN + n0);

  const float* rp = rspart + (size_t)b * 4 * NN + n0;
  f32x4 rlo, rhi;
#pragma unroll
  for (int q = 0; q < 4; q++) { rlo[q] = 0.f; rhi[q] = 0.f; }
#pragma unroll
  for (int p = 0; p < 4; p++) {
    f32x4 ra = *(const f32x4*)(rp + (size_t)p * NN);
    f32x4 rb = *(const f32x4*)(rp + (size_t)p * NN + 4);
#pragma unroll
    for (int q = 0; q < 4; q++) { rlo[q] += ra[q]; rhi[q] += rb[q]; }
  }

  const float* xp = x + ((size_t)b * CC + c) * NN + n0;
  f32x4 x0 = *(const f32x4*)(xp), x1 = *(const f32x4*)(xp + 4);
  float g = gamma[0];

  f32x4 o0, o1;
#pragma unroll
  for (int q = 0; q < 4; q++) {
    float a = bf16_to_f32((unsigned short)a0[q]) + bf16_to_f32((unsigned short)a1[q]);
    o0[q] = g * a / rlo[q] + x0[q];
    float a2 = bf16_to_f32((unsigned short)a0[q + 4]) + bf16_to_f32((unsigned short)a1[q + 4]);
    o1[q] = g * a2 / rhi[q] + x1[q];
  }
  float* op = out + ((size_t)b * CC + c) * NN + n0;
  *(f32x4*)op = o0;
  *(f32x4*)(op + 4) = o1;
}

extern "C" void kernel_launch(void* const* d_in, const int* in_sizes, int n_in,
                              void* d_out, int out_size, void* d_ws, size_t ws_size,
                              hipStream_t stream) {
  (void)in_sizes; (void)n_in; (void)out_size; (void)ws_size;
  const float* x  = (const float*)d_in[0];
  const float* qw = (const float*)d_in[1];
  const float* qb = (const float*)d_in[2];
  const float* kw = (const float*)d_in[3];
  const float* kb = (const float*)d_in[4];
  const float* vw = (const float*)d_in[5];
  const float* vb = (const float*)d_in[6];
  const float* gamma = (const float*)d_in[7];
  float* out = (float*)d_out;

  char* ws = (char*)d_ws;
  unsigned short* Wcat  = (unsigned short*)(ws);                       // 160 KB
  float*          bcat  = (float*)(ws + 163840);                       // 1.25 KB
  unsigned short* Qt    = (unsigned short*)(ws + 165120);              // 1 MB
  unsigned short* Kt    = (unsigned short*)(ws + 1213696);             // 1 MB
  unsigned short* V     = (unsigned short*)(ws + 2262272);             // 8 MB
  unsigned short* Apart = (unsigned short*)(ws + 10650880);            // 16 MB
  float*          rsprt = (float*)(ws + 27428096);                     // 256 KB

  hipLaunchKernelGGL(wconv_kernel, dim3(320), dim3(256), 0, stream,
                     qw, kw, vw, qb, kb, vb, Wcat, bcat);
  hipLaunchKernelGGL(proj_kernel, dim3(512), dim3(256), 0, stream,
                     x, Wcat, bcat, Qt, Kt, V);
  hipLaunchKernelGGL(attn_kernel, dim3(256), dim3(1024), 0, stream,
                     Qt, Kt, V, Apart, rsprt);
  hipLaunchKernelGGL(fuse_kernel, dim3(2048), dim3(256), 0, stream,
                     Apart, rsprt, x, gamma, out);
}